// Round 9
// baseline (148.653 us; speedup 1.0000x reference)
//
#include <hip/hip_runtime.h>
#include <hip/hip_bf16.h>

#define SEQ 4096
#define DM  512
#define NBLK 256

typedef short bf16x8 __attribute__((ext_vector_type(8)));
typedef short s16x4  __attribute__((ext_vector_type(4)));
typedef float f32x4  __attribute__((ext_vector_type(4)));

#define L2E 1.4426950408889634f
#define EXP2(x) __builtin_amdgcn_exp2f(x)
#define MFMA(a, b, c) __builtin_amdgcn_mfma_f32_16x16x32_bf16(a, b, c, 0, 0, 0)

static __device__ __forceinline__ unsigned short f2bf(float f) {
    unsigned int u = __builtin_bit_cast(unsigned int, f);
    unsigned int r = u + 0x7FFFu + ((u >> 16) & 1u);
    return (unsigned short)(r >> 16);
}

static __device__ __forceinline__ bf16x8 cvt8(const float* __restrict__ p, float s) {
    f32x4 a = *(const f32x4*)p;
    f32x4 b = *(const f32x4*)(p + 4);
    bf16x8 r;
    r[0] = (short)f2bf(a[0] * s); r[1] = (short)f2bf(a[1] * s);
    r[2] = (short)f2bf(a[2] * s); r[3] = (short)f2bf(a[3] * s);
    r[4] = (short)f2bf(b[0] * s); r[5] = (short)f2bf(b[1] * s);
    r[6] = (short)f2bf(b[2] * s); r[7] = (short)f2bf(b[3] * s);
    return r;
}

// Software grid barrier: all NBLK blocks co-resident (grid == #CUs).
// Writer: block-local sync, device fence, arrive; last sets monotonic flag.
static __device__ __forceinline__ void gbar(unsigned* ctr, unsigned* flag, unsigned gen) {
    __syncthreads();
    if (threadIdx.x == 0) {
        __threadfence();                       // release: device-scope visibility
        unsigned prev = atomicAdd(ctr, 1u);    // device-scope by default
        if (prev == NBLK - 1) {
            __hip_atomic_store(flag, gen, __ATOMIC_RELEASE, __HIP_MEMORY_SCOPE_AGENT);
        } else {
            while (__hip_atomic_load(flag, __ATOMIC_ACQUIRE, __HIP_MEMORY_SCOPE_AGENT) < gen)
                __builtin_amdgcn_s_sleep(4);
        }
        __threadfence();                       // acquire side
    }
    __syncthreads();
}

// ---------------------------------------------------------------------------
// One fused kernel. grid 256 x 512 threads, 68.6 KB LDS (1-2 blocks/CU, all
// 256 resident). Phase A: W/bias f32->bf16 (blocks 0..24; Wq,bq pre-scaled
// 1/8). gbar(1). Phase B: per-block 16-row QKV projection (E cvt inline;
// Q on waves 0-3, K on waves 4-7, V split-K over all 8). gbar(2).
// Phase C: causal flash attention (8 waves, 128 keys/wave-iter), LSE combine.
// ---------------------------------------------------------------------------
__global__ __launch_bounds__(512) void fused_kernel(
    const float* __restrict__ E,
    const float* __restrict__ Wq, const float* __restrict__ bq,
    const float* __restrict__ Wk, const float* __restrict__ bk,
    const float* __restrict__ Wv, const float* __restrict__ bv,
    unsigned short* __restrict__ Qb, unsigned short* __restrict__ Kb,
    unsigned short* __restrict__ VbT, unsigned short* __restrict__ Wbf,
    float* __restrict__ bsc, unsigned* __restrict__ bar,
    float* __restrict__ out)
{
    __shared__ __attribute__((aligned(16))) char smem[68608];

    const int bx  = (int)blockIdx.x;
    const int tid = (int)threadIdx.x;
    const int w   = tid >> 6;
    const int l   = tid & 63;
    const int lo  = l & 15;
    const int hi  = l >> 4;

    // ================= Phase A: weight/bias conversion ====================
    if (bx < 24) {
        int g = bx * 512 + tid;                  // 8-elem group id, 4096 per W
        int which = g >> 12;
        const float* W = (which == 0) ? Wq : ((which == 1) ? Wk : Wv);
        float s = (which == 0) ? 0.125f : 1.0f;
        size_t off = (size_t)(g & 4095) * 8;
        *(bf16x8*)&Wbf[(size_t)which * 32768 + off] = cvt8(&W[off], s);
    } else if (bx == 24) {
        if (tid < 64)       bsc[tid] = bq[tid] * 0.125f;
        else if (tid < 128) bsc[tid] = bk[tid - 64];
        else if (tid < 192) bsc[tid] = bv[tid - 128];
    }
    gbar(&bar[0], &bar[2], 1u);

    // ================= Phase B: 16-row QKV projection =====================
    const int r0 = bx * 16;
    {
        float* Acc = (float*)smem;               // [2][4][16][68] f32 (Q,K)
        const int unit = w >> 2;                 // 0=Q, 1=K
        const int ww   = w & 3;                  // split-K wave within unit
        const unsigned short* Wu = &Wbf[(size_t)unit * 32768];
        f32x4 acc[4] = {};
#pragma unroll
        for (int kk = 0; kk < 4; ++kk) {
            const int k0 = ww * 128 + kk * 32;
            bf16x8 a = cvt8(&E[(size_t)(r0 + lo) * DM + k0 + hi * 8], 1.0f);
#pragma unroll
            for (int ct = 0; ct < 4; ++ct) {
                bf16x8 bb = *(const bf16x8*)&Wu[(size_t)(lo + 16 * ct) * DM + k0 + hi * 8];
                acc[ct] = MFMA(a, bb, acc[ct]);
            }
        }
#pragma unroll
        for (int ct = 0; ct < 4; ++ct)
#pragma unroll
            for (int r = 0; r < 4; ++r)
                Acc[unit * 4352 + (ww * 16 + hi * 4 + r) * 68 + lo + 16 * ct] = acc[ct][r];
        __syncthreads();
        {   // reduce Q (threads 0..255) and K (256..511)
            const int u2  = tid >> 8;
            const int t2  = tid & 255;
            const int row = t2 >> 4;
            const int c0  = (t2 & 15) * 4;
            f32x4 sum = {};
#pragma unroll
            for (int p = 0; p < 4; ++p)
                sum += *(const f32x4*)&Acc[u2 * 4352 + (p * 16 + row) * 68 + c0];
            const float* bias = &bsc[u2 * 64];
            unsigned short* dst = u2 ? Kb : Qb;
            s16x4 o4;
#pragma unroll
            for (int j = 0; j < 4; ++j)
                o4[j] = (short)f2bf(sum[j] + bias[c0 + j]);
            *(s16x4*)&dst[(size_t)(r0 + row) * 64 + c0] = o4;
        }
        __syncthreads();                         // before reusing smem for V

        // V: split-K over all 8 waves (64 k-cols each)
        float* VAcc = (float*)smem;              // [8][64][20] f32
        f32x4 vacc[4] = {};
#pragma unroll
        for (int kk = 0; kk < 2; ++kk) {
            const int k0 = w * 64 + kk * 32;
            bf16x8 bb = cvt8(&E[(size_t)(r0 + lo) * DM + k0 + hi * 8], 1.0f);
#pragma unroll
            for (int ct = 0; ct < 4; ++ct) {
                bf16x8 a = *(const bf16x8*)&Wbf[(size_t)(2 * 32768) + (size_t)(lo + 16 * ct) * DM + k0 + hi * 8];
                vacc[ct] = MFMA(a, bb, vacc[ct]);
            }
        }
#pragma unroll
        for (int ct = 0; ct < 4; ++ct)
#pragma unroll
            for (int r = 0; r < 4; ++r)
                VAcc[(w * 64 + 16 * ct + hi * 4 + r) * 20 + lo] = vacc[ct][r];
        __syncthreads();
        {   // reduce V: thread -> (d, 2 seq cols)
            const int d  = tid >> 3;
            const int n2 = (tid & 7) * 2;
            float s0 = 0.f, s1 = 0.f;
#pragma unroll
            for (int p = 0; p < 8; ++p) {
                s0 += VAcc[(p * 64 + d) * 20 + n2];
                s1 += VAcc[(p * 64 + d) * 20 + n2 + 1];
            }
            const float bd = bsc[128 + d];
            union { unsigned u32; unsigned short u16[2]; } vo;
            vo.u16[0] = f2bf(s0 + bd);
            vo.u16[1] = f2bf(s1 + bd);
            *(unsigned*)&VbT[(size_t)d * SEQ + r0 + n2] = vo.u32;
        }
    }
    gbar(&bar[1], &bar[2], 2u);

    // ================= Phase C: causal flash attention ====================
    const int q0 = r0;
    unsigned short (*Pl)[16][136] = (unsigned short(*)[16][136])smem;      // 34816 B
    float (*Osh)[16][64] = (float(*)[16][64])(smem + 34816);               // 32768 B
    float (*msh)[16] = (float(*)[16])(smem + 67584);
    float (*lsh)[16] = (float(*)[16])(smem + 68096);

    bf16x8 qf0 = *(const bf16x8*)&Qb[(size_t)(q0 + lo) * 64 + hi * 8];
    bf16x8 qf1 = *(const bf16x8*)&Qb[(size_t)(q0 + lo) * 64 + 32 + hi * 8];

    float m[4], lsum[4];
    f32x4 o[4] = {};
#pragma unroll
    for (int r = 0; r < 4; ++r) { m[r] = -1e30f; lsum[r] = 0.f; }

    const int kend = q0 + 16;
    for (int kb = w * 128; kb < kend; kb += 1024) {
        const bool hasB = (kb + 64 < kend);
        f32x4 s[8] = {};
#pragma unroll
        for (int ct = 0; ct < 4; ++ct) {
            const unsigned short* kp = &Kb[(size_t)(kb + lo + 16 * ct) * 64];
            bf16x8 kf0 = *(const bf16x8*)&kp[hi * 8];
            bf16x8 kf1 = *(const bf16x8*)&kp[32 + hi * 8];
            s[ct] = MFMA(qf0, kf0, s[ct]);
            s[ct] = MFMA(qf1, kf1, s[ct]);
        }
        if (hasB) {
#pragma unroll
            for (int ct = 0; ct < 4; ++ct) {
                const unsigned short* kp = &Kb[(size_t)(kb + 64 + lo + 16 * ct) * 64];
                bf16x8 kf0 = *(const bf16x8*)&kp[hi * 8];
                bf16x8 kf1 = *(const bf16x8*)&kp[32 + hi * 8];
                s[4 + ct] = MFMA(qf0, kf0, s[4 + ct]);
                s[4 + ct] = MFMA(qf1, kf1, s[4 + ct]);
            }
        }
        if (kb + 63 > q0) {
#pragma unroll
            for (int ct = 0; ct < 4; ++ct) {
                int key = kb + lo + 16 * ct;
#pragma unroll
                for (int r = 0; r < 4; ++r)
                    if (key > q0 + hi * 4 + r) s[ct][r] = -3.0e38f;
            }
        }
        if (hasB && (kb + 127 > q0)) {
#pragma unroll
            for (int ct = 0; ct < 4; ++ct) {
                int key = kb + 64 + lo + 16 * ct;
#pragma unroll
                for (int r = 0; r < 4; ++r)
                    if (key > q0 + hi * 4 + r) s[4 + ct][r] = -3.0e38f;
            }
        }
        float mt[4] = { -1e30f, -1e30f, -1e30f, -1e30f };
#pragma unroll
        for (int ct = 0; ct < 4; ++ct)
#pragma unroll
            for (int r = 0; r < 4; ++r) mt[r] = fmaxf(mt[r], s[ct][r]);
        if (hasB) {
#pragma unroll
            for (int ct = 0; ct < 4; ++ct)
#pragma unroll
                for (int r = 0; r < 4; ++r) mt[r] = fmaxf(mt[r], s[4 + ct][r]);
        }
#pragma unroll
        for (int mask = 1; mask < 16; mask <<= 1)
#pragma unroll
            for (int r = 0; r < 4; ++r) mt[r] = fmaxf(mt[r], __shfl_xor(mt[r], mask));
        float alpha[4], mn[4];
#pragma unroll
        for (int r = 0; r < 4; ++r) {
            mn[r] = fmaxf(m[r], mt[r]);
            alpha[r] = EXP2((m[r] - mn[r]) * L2E);
            m[r] = mn[r];
        }
        float ps[4] = { 0.f, 0.f, 0.f, 0.f };
#pragma unroll
        for (int ct = 0; ct < 4; ++ct) {
#pragma unroll
            for (int r = 0; r < 4; ++r) {
                float p = EXP2((s[ct][r] - mn[r]) * L2E);
                ps[r] += p;
                Pl[w][hi * 4 + r][lo + 16 * ct] = f2bf(p);
            }
        }
        if (hasB) {
#pragma unroll
            for (int ct = 0; ct < 4; ++ct) {
#pragma unroll
                for (int r = 0; r < 4; ++r) {
                    float p = EXP2((s[4 + ct][r] - mn[r]) * L2E);
                    ps[r] += p;
                    Pl[w][hi * 4 + r][64 + lo + 16 * ct] = f2bf(p);
                }
            }
        }
#pragma unroll
        for (int mask = 1; mask < 16; mask <<= 1)
#pragma unroll
            for (int r = 0; r < 4; ++r) ps[r] += __shfl_xor(ps[r], mask);
#pragma unroll
        for (int r = 0; r < 4; ++r) lsum[r] = lsum[r] * alpha[r] + ps[r];
#pragma unroll
        for (int dt = 0; dt < 4; ++dt)
#pragma unroll
            for (int r = 0; r < 4; ++r) o[dt][r] *= alpha[r];
        bf16x8 pa0 = *(const bf16x8*)&Pl[w][lo][hi * 8];
        bf16x8 pa1 = *(const bf16x8*)&Pl[w][lo][32 + hi * 8];
#pragma unroll
        for (int dt = 0; dt < 4; ++dt) {
            const unsigned short* vp = &VbT[(size_t)(lo + 16 * dt) * SEQ + kb];
            bf16x8 v0 = *(const bf16x8*)&vp[hi * 8];
            bf16x8 v1 = *(const bf16x8*)&vp[32 + hi * 8];
            o[dt] = MFMA(pa0, v0, o[dt]);
            o[dt] = MFMA(pa1, v1, o[dt]);
        }
        if (hasB) {
            bf16x8 pa2 = *(const bf16x8*)&Pl[w][lo][64 + hi * 8];
            bf16x8 pa3 = *(const bf16x8*)&Pl[w][lo][96 + hi * 8];
#pragma unroll
            for (int dt = 0; dt < 4; ++dt) {
                const unsigned short* vp = &VbT[(size_t)(lo + 16 * dt) * SEQ + kb + 64];
                bf16x8 v2 = *(const bf16x8*)&vp[hi * 8];
                bf16x8 v3 = *(const bf16x8*)&vp[32 + hi * 8];
                o[dt] = MFMA(pa2, v2, o[dt]);
                o[dt] = MFMA(pa3, v3, o[dt]);
            }
        }
    }

#pragma unroll
    for (int dt = 0; dt < 4; ++dt)
#pragma unroll
        for (int r = 0; r < 4; ++r)
            Osh[w][hi * 4 + r][lo + 16 * dt] = o[dt][r];
    if (lo == 0) {
#pragma unroll
        for (int r = 0; r < 4; ++r) {
            msh[w][hi * 4 + r] = m[r];
            lsh[w][hi * 4 + r] = lsum[r];
        }
    }
    __syncthreads();

    {
        const int q  = tid >> 5;
        const int d0 = (tid & 31) * 2;
        float M = msh[0][q];
#pragma unroll
        for (int p = 1; p < 8; ++p) M = fmaxf(M, msh[p][q]);
        float L = 0.f, a0 = 0.f, a1 = 0.f;
#pragma unroll
        for (int p = 0; p < 8; ++p) {
            float e = EXP2((msh[p][q] - M) * L2E);
            L  += e * lsh[p][q];
            a0 += e * Osh[p][q][d0];
            a1 += e * Osh[p][q][d0 + 1];
        }
        float inv = 1.0f / L;
        out[(size_t)(q0 + q) * 64 + d0]     = a0 * inv;
        out[(size_t)(q0 + q) * 64 + d0 + 1] = a1 * inv;
    }
}

// ---------------------------------------------------------------------------
extern "C" void kernel_launch(void* const* d_in, const int* in_sizes, int n_in,
                              void* d_out, int out_size, void* d_ws, size_t ws_size,
                              hipStream_t stream) {
    const float* E  = (const float*)d_in[0];
    const float* Wq = (const float*)d_in[1];
    const float* bq = (const float*)d_in[2];
    const float* Wk = (const float*)d_in[3];
    const float* bk = (const float*)d_in[4];
    const float* Wv = (const float*)d_in[5];
    const float* bv = (const float*)d_in[6];
    float* out = (float*)d_out;

    char* ws = (char*)d_ws;
    unsigned short* Qb  = (unsigned short*)(ws);                    // 512 KB
    unsigned short* Kb  = (unsigned short*)(ws + (512u << 10));     // 512 KB
    unsigned short* VbT = (unsigned short*)(ws + (1024u << 10));    // 512 KB
    unsigned short* Wbf = (unsigned short*)(ws + (1536u << 10));    // 192 KB
    float*          bsc = (float*)(ws + (1792u << 10));             // 768 B
    unsigned*       bar = (unsigned*)(ws + (2048u << 10));          // 16 B

    hipMemsetAsync(bar, 0, 16, stream);
    hipLaunchKernelGGL(fused_kernel, dim3(NBLK), dim3(512), 0, stream,
                       E, Wq, bq, Wk, bk, Wv, bv, Qb, Kb, VbT, Wbf, bsc, bar, out);
}

// Round 10
// 111.734 us; speedup vs baseline: 1.3304x; 1.3304x over previous
//
#include <hip/hip_runtime.h>
#include <hip/hip_bf16.h>

#define SEQ 4096
#define DM  512

typedef short bf16x8 __attribute__((ext_vector_type(8)));
typedef short s16x4  __attribute__((ext_vector_type(4)));
typedef float f32x4  __attribute__((ext_vector_type(4)));

#define L2E 1.4426950408889634f
#define EXP2(x) __builtin_amdgcn_exp2f(x)

static __device__ __forceinline__ unsigned short f2bf(float f) {
    unsigned int u = __builtin_bit_cast(unsigned int, f);
    unsigned int r = u + 0x7FFFu + ((u >> 16) & 1u);
    return (unsigned short)(r >> 16);
}

static __device__ __forceinline__ bf16x8 cvt8(const float* __restrict__ p, float s) {
    f32x4 a = *(const f32x4*)p;
    f32x4 b = *(const f32x4*)(p + 4);
    bf16x8 r;
    r[0] = (short)f2bf(a[0] * s); r[1] = (short)f2bf(a[1] * s);
    r[2] = (short)f2bf(a[2] * s); r[3] = (short)f2bf(a[3] * s);
    r[4] = (short)f2bf(b[0] * s); r[5] = (short)f2bf(b[1] * s);
    r[6] = (short)f2bf(b[2] * s); r[7] = (short)f2bf(b[3] * s);
    return r;
}

// ---------------------------------------------------------------------------
// Kernel 0: one-shot f32->bf16 conversion.
//   blocks 0..1023:  E -> Ebf  (2M elems, 8/thread)
//   blocks 1024..1071: Wq|Wk|Wv -> Wbf (Wq pre-scaled by 0.125)
//   block 1072: biases -> bsc f32 (bq pre-scaled by 0.125)
// ---------------------------------------------------------------------------
__global__ __launch_bounds__(256) void cvt_kernel(
    const float* __restrict__ E,
    const float* __restrict__ Wq, const float* __restrict__ bq,
    const float* __restrict__ Wk, const float* __restrict__ bk,
    const float* __restrict__ Wv, const float* __restrict__ bv,
    unsigned short* __restrict__ Ebf, unsigned short* __restrict__ Wbf,
    float* __restrict__ bsc)
{
    const int b = (int)blockIdx.x;
    const int t = (int)threadIdx.x;
    if (b < 1024) {
        size_t off = (size_t)b * 2048 + (size_t)t * 8;
        *(bf16x8*)&Ebf[off] = cvt8(&E[off], 1.0f);
    } else if (b < 1072) {
        int i = b - 1024;                 // 16 blocks per W matrix
        int which = i >> 4;
        const float* W = (which == 0) ? Wq : ((which == 1) ? Wk : Wv);
        float s = (which == 0) ? 0.125f : 1.0f;
        size_t woff = (size_t)(i & 15) * 2048 + (size_t)t * 8;
        *(bf16x8*)&Wbf[(size_t)which * 32768 + woff] = cvt8(&W[woff], s);
    } else {
        if (t < 64)       bsc[t] = bq[t] * 0.125f;
        else if (t < 128) bsc[t] = bk[t - 64];
        else if (t < 192) bsc[t] = bv[t - 128];
    }
}

// ---------------------------------------------------------------------------
// Kernel 1: QKV projection from bf16 inputs, split-K across 4 waves + LDS
//   f32 reduce. grid (SEQ/16, 3), block 256. blockIdx.y: 0=Q,1=K,2=V(transp).
//   Q: [SEQ][64] bf16, PRE-SCALED by 1/8 (Wq,bq scaled upstream).
//   K: [SEQ][64] bf16.  V: VbT[d][n] = V^T, [64][SEQ] bf16.
// ---------------------------------------------------------------------------
__global__ __launch_bounds__(256) void proj_kernel(
    const unsigned short* __restrict__ Ebf,
    const unsigned short* __restrict__ Wbf,
    const float* __restrict__ bsc,
    unsigned short* __restrict__ Qb, unsigned short* __restrict__ Kb,
    unsigned short* __restrict__ VbT)
{
    const int which = blockIdx.y;
    const int bx  = blockIdx.x;
    const int tid = (int)threadIdx.x;
    const int w   = tid >> 6;             // wave 0..3: K-chunk w*128
    const int l   = tid & 63;
    const int lo  = l & 15;
    const int hi  = l >> 4;

    __shared__ float Acc[5120];           // Q/K: [4][16][68]; V: [4][64][20]

    const unsigned short* W = &Wbf[(size_t)which * 32768];
    const float* bias = &bsc[which * 64];

    f32x4 acc[4] = {};

    if (which < 2) {
        unsigned short* out = (which == 0) ? Qb : Kb;
        const int r0 = bx * 16;
#pragma unroll
        for (int kk = 0; kk < 4; ++kk) {
            const int k0 = w * 128 + kk * 32;
            bf16x8 a = *(const bf16x8*)&Ebf[(size_t)(r0 + lo) * DM + k0 + hi * 8];
#pragma unroll
            for (int ct = 0; ct < 4; ++ct) {
                bf16x8 bb = *(const bf16x8*)&W[(size_t)(lo + 16 * ct) * DM + k0 + hi * 8];
                acc[ct] = __builtin_amdgcn_mfma_f32_16x16x32_bf16(a, bb, acc[ct], 0, 0, 0);
            }
        }
#pragma unroll
        for (int ct = 0; ct < 4; ++ct)
#pragma unroll
            for (int r = 0; r < 4; ++r)
                Acc[(w * 16 + hi * 4 + r) * 68 + lo + 16 * ct] = acc[ct][r];
        __syncthreads();
        {
            const int row = tid >> 4;
            const int c0  = (tid & 15) * 4;
            f32x4 sum = {};
#pragma unroll
            for (int ww = 0; ww < 4; ++ww)
                sum += *(const f32x4*)&Acc[(ww * 16 + row) * 68 + c0];
            s16x4 o4;
#pragma unroll
            for (int j = 0; j < 4; ++j)
                o4[j] = (short)f2bf(sum[j] + bias[c0 + j]);
            *(s16x4*)&out[(size_t)(r0 + row) * 64 + c0] = o4;
        }
    } else {
        const int n0 = bx * 16;
#pragma unroll
        for (int kk = 0; kk < 4; ++kk) {
            const int k0 = w * 128 + kk * 32;
            bf16x8 bb = *(const bf16x8*)&Ebf[(size_t)(n0 + lo) * DM + k0 + hi * 8];
#pragma unroll
            for (int ct = 0; ct < 4; ++ct) {
                bf16x8 a = *(const bf16x8*)&W[(size_t)(lo + 16 * ct) * DM + k0 + hi * 8];
                acc[ct] = __builtin_amdgcn_mfma_f32_16x16x32_bf16(a, bb, acc[ct], 0, 0, 0);
            }
        }
#pragma unroll
        for (int ct = 0; ct < 4; ++ct)
#pragma unroll
            for (int r = 0; r < 4; ++r)
                Acc[(w * 64 + 16 * ct + hi * 4 + r) * 20 + lo] = acc[ct][r];
        __syncthreads();
        {
            const int d  = tid >> 2;
            const int n4 = (tid & 3) * 4;
            f32x4 sum = {};
#pragma unroll
            for (int ww = 0; ww < 4; ++ww)
                sum += *(const f32x4*)&Acc[(ww * 64 + d) * 20 + n4];
            const float bd = bias[d];
            s16x4 o4;
#pragma unroll
            for (int j = 0; j < 4; ++j)
                o4[j] = (short)f2bf(sum[j] + bd);
            *(s16x4*)&VbT[(size_t)d * SEQ + n0 + n4] = o4;
        }
    }
}

// ---------------------------------------------------------------------------
// Kernel 2: causal flash attention, single pass, 8 waves per block.
//   grid (SEQ/16), block 512. Wave w takes k-blocks w, w+8, ...
//   Q pre-scaled => no per-element scale. Exactly ONE partially-masked
//   k-block per q-tile (kb <= q0 always; masked iff kb+63 > q0) => the
//   mask path is a wave-uniform branch taken once.
// ---------------------------------------------------------------------------
__global__ __launch_bounds__(512) void attn_kernel(
    const unsigned short* __restrict__ Qb,
    const unsigned short* __restrict__ Kb,
    const unsigned short* __restrict__ VbT,
    float* __restrict__ out)
{
    const int q0  = blockIdx.x * 16;
    const int tid = (int)threadIdx.x;
    const int w   = tid >> 6;
    const int l   = tid & 63;
    const int lo  = l & 15;
    const int hi  = l >> 4;

    __shared__ unsigned short Pl[8][16][80];
    __shared__ float Osh[8][16][64];
    __shared__ float msh[8][16];
    __shared__ float lsh[8][16];

    bf16x8 qf0 = *(const bf16x8*)&Qb[(size_t)(q0 + lo) * 64 + hi * 8];
    bf16x8 qf1 = *(const bf16x8*)&Qb[(size_t)(q0 + lo) * 64 + 32 + hi * 8];

    float m[4], lsum[4];
    f32x4 o[4] = {};
#pragma unroll
    for (int r = 0; r < 4; ++r) { m[r] = -1e30f; lsum[r] = 0.f; }

    const int kend = q0 + 16;
    for (int kb = w * 64; kb < kend; kb += 512) {
        // ---- QK^T (16 q x 64 k) ----
        f32x4 s[4] = {};
#pragma unroll
        for (int ct = 0; ct < 4; ++ct) {
            bf16x8 kf0 = *(const bf16x8*)&Kb[(size_t)(kb + lo + 16 * ct) * 64 + hi * 8];
            bf16x8 kf1 = *(const bf16x8*)&Kb[(size_t)(kb + lo + 16 * ct) * 64 + 32 + hi * 8];
            s[ct] = __builtin_amdgcn_mfma_f32_16x16x32_bf16(qf0, kf0, s[ct], 0, 0, 0);
            s[ct] = __builtin_amdgcn_mfma_f32_16x16x32_bf16(qf1, kf1, s[ct], 0, 0, 0);
        }
        // ---- causal mask (one block per tile) + row max ----
        float mt[4] = { -1e30f, -1e30f, -1e30f, -1e30f };
        if (kb + 63 > q0) {
#pragma unroll
            for (int ct = 0; ct < 4; ++ct) {
                int key = kb + lo + 16 * ct;
#pragma unroll
                for (int r = 0; r < 4; ++r) {
                    float v = s[ct][r];
                    if (key > q0 + hi * 4 + r) v = -3.0e38f;
                    s[ct][r] = v;
                    mt[r] = fmaxf(mt[r], v);
                }
            }
        } else {
#pragma unroll
            for (int ct = 0; ct < 4; ++ct)
#pragma unroll
                for (int r = 0; r < 4; ++r) mt[r] = fmaxf(mt[r], s[ct][r]);
        }
#pragma unroll
        for (int mask = 1; mask < 16; mask <<= 1)
#pragma unroll
            for (int r = 0; r < 4; ++r) mt[r] = fmaxf(mt[r], __shfl_xor(mt[r], mask));
        // ---- online softmax update ----
        float alpha[4], mn[4];
#pragma unroll
        for (int r = 0; r < 4; ++r) {
            mn[r] = fmaxf(m[r], mt[r]);
            alpha[r] = EXP2((m[r] - mn[r]) * L2E);
            m[r] = mn[r];
        }
        float ps[4] = { 0.f, 0.f, 0.f, 0.f };
#pragma unroll
        for (int ct = 0; ct < 4; ++ct) {
#pragma unroll
            for (int r = 0; r < 4; ++r) {
                float p = EXP2((s[ct][r] - mn[r]) * L2E);
                s[ct][r] = p;
                ps[r] += p;
            }
        }
#pragma unroll
        for (int mask = 1; mask < 16; mask <<= 1)
#pragma unroll
            for (int r = 0; r < 4; ++r) ps[r] += __shfl_xor(ps[r], mask);
#pragma unroll
        for (int r = 0; r < 4; ++r) lsum[r] = lsum[r] * alpha[r] + ps[r];
#pragma unroll
        for (int dt = 0; dt < 4; ++dt)
#pragma unroll
            for (int r = 0; r < 4; ++r) o[dt][r] *= alpha[r];
        // ---- P -> bf16 -> per-wave LDS (re-fragment for PV) ----
#pragma unroll
        for (int ct = 0; ct < 4; ++ct)
#pragma unroll
            for (int r = 0; r < 4; ++r)
                Pl[w][hi * 4 + r][lo + 16 * ct] = f2bf(s[ct][r]);
        asm volatile("" ::: "memory");
        bf16x8 pa0 = *(const bf16x8*)&Pl[w][lo][hi * 8];
        bf16x8 pa1 = *(const bf16x8*)&Pl[w][lo][32 + hi * 8];
        // ---- PV ----
#pragma unroll
        for (int dt = 0; dt < 4; ++dt) {
            bf16x8 v0 = *(const bf16x8*)&VbT[(size_t)(lo + 16 * dt) * SEQ + kb + hi * 8];
            bf16x8 v1 = *(const bf16x8*)&VbT[(size_t)(lo + 16 * dt) * SEQ + kb + 32 + hi * 8];
            o[dt] = __builtin_amdgcn_mfma_f32_16x16x32_bf16(pa0, v0, o[dt], 0, 0, 0);
            o[dt] = __builtin_amdgcn_mfma_f32_16x16x32_bf16(pa1, v1, o[dt], 0, 0, 0);
        }
        asm volatile("" ::: "memory");
    }

    // ---- stage wave partials in LDS ----
#pragma unroll
    for (int dt = 0; dt < 4; ++dt)
#pragma unroll
        for (int r = 0; r < 4; ++r)
            Osh[w][hi * 4 + r][lo + 16 * dt] = o[dt][r];
    if (lo == 0) {
#pragma unroll
        for (int r = 0; r < 4; ++r) {
            msh[w][hi * 4 + r] = m[r];
            lsh[w][hi * 4 + r] = lsum[r];
        }
    }
    __syncthreads();

    // ---- combine the 8 wave partials (LSE), write normalized output ----
    {
        const int q  = tid >> 5;
        const int d0 = (tid & 31) * 2;
        float M = msh[0][q];
#pragma unroll
        for (int ww = 1; ww < 8; ++ww) M = fmaxf(M, msh[ww][q]);
        float L = 0.f, a0 = 0.f, a1 = 0.f;
#pragma unroll
        for (int ww = 0; ww < 8; ++ww) {
            float e = EXP2((msh[ww][q] - M) * L2E);
            L  += e * lsh[ww][q];
            a0 += e * Osh[ww][q][d0];
            a1 += e * Osh[ww][q][d0 + 1];
        }
        float inv = 1.0f / L;
        out[(size_t)(q0 + q) * 64 + d0]     = a0 * inv;
        out[(size_t)(q0 + q) * 64 + d0 + 1] = a1 * inv;
    }
}

// ---------------------------------------------------------------------------
extern "C" void kernel_launch(void* const* d_in, const int* in_sizes, int n_in,
                              void* d_out, int out_size, void* d_ws, size_t ws_size,
                              hipStream_t stream) {
    const float* E  = (const float*)d_in[0];
    const float* Wq = (const float*)d_in[1];
    const float* bq = (const float*)d_in[2];
    const float* Wk = (const float*)d_in[3];
    const float* bk = (const float*)d_in[4];
    const float* Wv = (const float*)d_in[5];
    const float* bv = (const float*)d_in[6];
    float* out = (float*)d_out;

    char* ws = (char*)d_ws;
    unsigned short* Qb  = (unsigned short*)(ws);                    // 512 KB
    unsigned short* Kb  = (unsigned short*)(ws + (512u << 10));     // 512 KB
    unsigned short* VbT = (unsigned short*)(ws + (1024u << 10));    // 512 KB
    unsigned short* Ebf = (unsigned short*)(ws + (1536u << 10));    // 4 MB
    unsigned short* Wbf = (unsigned short*)(ws + (5632u << 10));    // 192 KB
    float*          bsc = (float*)(ws + (5888u << 10));             // 768 B

    hipLaunchKernelGGL(cvt_kernel, dim3(1073), dim3(256), 0, stream,
                       E, Wq, bq, Wk, bk, Wv, bv, Ebf, Wbf, bsc);
    hipLaunchKernelGGL(proj_kernel, dim3(SEQ / 16, 3), dim3(256), 0, stream,
                       Ebf, Wbf, bsc, Qb, Kb, VbT);
    hipLaunchKernelGGL(attn_kernel, dim3(SEQ / 16), dim3(512), 0, stream,
                       Qb, Kb, VbT, out);
}